// Round 1
// baseline (654.809 us; speedup 1.0000x reference)
//
#include <hip/hip_runtime.h>
#include <math.h>

#define D_MODEL 1024
#define N_EXP   16
#define SEQ     4096
#define NBATCH  4
#define NTOK    (NBATCH*SEQ)
#define DFFN    32
#define DTASK   64

// ws layout (bytes)
#define WS_SUMS   0                      // double[8]  (per batch: sum, sumsq)
#define WS_RS     64                     // float[4]
#define WS_MU     80                     // float[4]
#define WS_GB     128                    // float[64]  (4 batches x 16 experts)
#define WS_CNT    512                    // int[2][16]
#define WS_TOKREC 1024                   // float4[NTOK]
#define WS_BUCKET (1024 + NTOK*16)       // int[2][16][NTOK]

#define OUT_LB  (NTOK*D_MODEL)
#define OUT_IDX (NTOK*D_MODEL + 1)

__device__ __forceinline__ void atomAddF(float* p, float v) {
  unsafeAtomicAdd(p, v);   // hw global_atomic_add_f32 on gfx950
}

// ---------------- stats: per-batch sum / sumsq over 4M elems ----------------
__global__ __launch_bounds__(256) void k_stats(const float* __restrict__ x,
                                               double* __restrict__ sums) {
  int b = blockIdx.y;
  const float4* xb = (const float4*)(x + (size_t)b * SEQ * D_MODEL);
  const int n4 = SEQ * D_MODEL / 4;
  double s = 0.0, ss = 0.0;
  for (int i = blockIdx.x * 256 + threadIdx.x; i < n4; i += gridDim.x * 256) {
    float4 v = xb[i];
    s  += (double)v.x + (double)v.y + (double)v.z + (double)v.w;
    ss += (double)v.x*v.x + (double)v.y*v.y + (double)v.z*v.z + (double)v.w*v.w;
  }
  __shared__ double r0[256], r1[256];
  r0[threadIdx.x] = s; r1[threadIdx.x] = ss;
  __syncthreads();
  for (int off = 128; off > 0; off >>= 1) {
    if (threadIdx.x < off) { r0[threadIdx.x] += r0[threadIdx.x+off]; r1[threadIdx.x] += r1[threadIdx.x+off]; }
    __syncthreads();
  }
  if (threadIdx.x == 0) { atomicAdd(&sums[2*b], r0[0]); atomicAdd(&sums[2*b+1], r1[0]); }
}

// ---------------- prep: mu/rs, Wg colsums, per-(b,e) gating offsets --------
__global__ __launch_bounds__(256) void k_prep(const double* __restrict__ sums,
    const int* __restrict__ task_id, const float* __restrict__ task_emb,
    const float* __restrict__ Wg, const float* __restrict__ bg,
    float* __restrict__ wsf) {
  __shared__ float smu[4], srs[4], sSe[16];
  __shared__ float red[16][16];
  int tid = threadIdx.x;
  if (tid < 4) {
    double n = (double)SEQ * (double)D_MODEL;
    double mu = sums[2*tid] / n;
    double var = sums[2*tid+1] / n - mu*mu;
    float rsv = (float)(1.0 / sqrt(var + 1e-5));
    smu[tid] = (float)mu; srs[tid] = rsv;
    wsf[WS_RS/4 + tid] = rsv; wsf[WS_MU/4 + tid] = (float)mu;
  }
  {
    int e = tid & 15, part = tid >> 4;
    float p = 0.f;
    for (int r = part*64; r < part*64 + 64; ++r) p += Wg[r*N_EXP + e];
    red[part][e] = p;
  }
  __syncthreads();
  if (tid < 16) {
    float t = 0.f;
    for (int i = 0; i < 16; ++i) t += red[i][tid];
    sSe[tid] = t;
  }
  __syncthreads();
  if (tid < 64) {
    int b = tid >> 4, e = tid & 15;
    int tk = task_id[b];
    float off = 0.f;
    for (int j = 0; j < DTASK; ++j)
      off += task_emb[tk*DTASK + j] * Wg[(D_MODEL + j)*N_EXP + e];
    wsf[WS_GB/4 + tid] = bg[e] + off - srs[b]*smu[b]*sSe[e];
  }
}

// ---------------- gating: logits, top-2, softmax, bucket scatter -----------
__global__ __launch_bounds__(256) void k_gating(const float* __restrict__ x,
    const float* __restrict__ Wg, const float* __restrict__ wsf,
    float* __restrict__ out, float4* __restrict__ tokrec,
    int* __restrict__ cnt, int* __restrict__ bucket) {
  __shared__ float wgT[N_EXP][D_MODEL + 1];  // transposed + pad: conflict-free
  __shared__ float lg[4][4][16];             // [wave][tok-in-iter][expert]
  int tid = threadIdx.x;
  for (int i = tid; i < D_MODEL*N_EXP/4; i += 256) {
    float4 v = ((const float4*)Wg)[i];
    int d = i >> 2, e0 = (i & 3) << 2;
    wgT[e0+0][d] = v.x; wgT[e0+1][d] = v.y; wgT[e0+2][d] = v.z; wgT[e0+3][d] = v.w;
  }
  __syncthreads();
  int wave = tid >> 6, lane = tid & 63;
  int blk0 = blockIdx.x * 64;
  int b = blk0 >> 12;          // 64 | 4096 -> whole block in one batch
  float rsb = wsf[WS_RS/4 + b];
  for (int it = 0; it < 4; ++it) {
    int tbase = blk0 + wave*16 + it*4;
    float xr[4][16];
    #pragma unroll
    for (int tt = 0; tt < 4; ++tt) {
      const float* xp = x + (size_t)(tbase + tt)*D_MODEL + lane;
      #pragma unroll
      for (int j = 0; j < 16; ++j) xr[tt][j] = xp[j*64];
    }
    float v[64];
    #pragma unroll
    for (int i = 0; i < 64; ++i) v[i] = 0.f;
    #pragma unroll
    for (int j = 0; j < 16; ++j) {
      int d = lane + 64*j;
      #pragma unroll
      for (int e = 0; e < 16; ++e) {
        float w = wgT[e][d];
        #pragma unroll
        for (int tt = 0; tt < 4; ++tt) v[tt*16 + e] = fmaf(xr[tt][j], w, v[tt*16 + e]);
      }
    }
    // butterfly transpose-reduce: lane l ends with full dot of pair p = l
    #pragma unroll
    for (int m = 32; m >= 1; m >>= 1) {
      #pragma unroll
      for (int j2 = 0; j2 < m; ++j2) {
        float lo = v[j2], hi = v[j2 + m];
        bool up = (lane & m) != 0;
        float mine = up ? hi : lo;
        float theirs = up ? lo : hi;
        v[j2] = mine + __shfl_xor(theirs, m, 64);
      }
    }
    int e = lane & 15, tt = lane >> 4;
    float logit = fmaf(rsb, v[0], wsf[WS_GB/4 + b*16 + e]);
    lg[wave][tt][e] = logit;
    __syncthreads();
    if ((lane & 15) == 0) {
      int token = tbase + tt;
      float v0 = -1e30f, v1 = -1e30f; int i0 = 0, i1 = 0;
      #pragma unroll
      for (int ee = 0; ee < 16; ++ee) {
        float L = lg[wave][tt][ee];
        if (L > v0)      { v1 = v0; i1 = i0; v0 = L; i0 = ee; }
        else if (L > v1) { v1 = L; i1 = ee; }
      }
      float ex = __expf(v1 - v0);
      float p0 = 1.f / (1.f + ex);
      float p1 = ex * p0;
      out[OUT_IDX + token*2 + 0] = (float)i0;
      out[OUT_IDX + token*2 + 1] = (float)i1;
      tokrec[token] = make_float4(__int_as_float(i0), __int_as_float(i1), p0, p1);
      int pos0 = atomicAdd(&cnt[i0], 1);
      bucket[i0*NTOK + pos0] = token;
      int pos1 = atomicAdd(&cnt[16 + i1], 1);
      bucket[16*NTOK + i1*NTOK + pos1] = token;
    }
    __syncthreads();
  }
}

// ---------------- grouped FFN: 64 tokens/block, one expert -----------------
// MODE 0: k=0 assignments, plain store + both bias terms (full coverage)
// MODE 1: k=1 assignments, atomicAdd
template<int MODE>
__global__ __launch_bounds__(256) void k_ffn(const float* __restrict__ x,
    const float* __restrict__ W1, const float* __restrict__ b1,
    const float* __restrict__ W2, const float* __restrict__ b2,
    const float4* __restrict__ tokrec, const int* __restrict__ cnt,
    const int* __restrict__ bucket, float* __restrict__ out) {
  int e = blockIdx.y;
  int cntE = cnt[MODE*16 + e];
  int r0 = blockIdx.x * 64;
  if (r0 >= cntE) return;
  int R = min(64, cntE - r0);

  __shared__ int   toks[64];
  __shared__ float wself[64], woth[64];
  __shared__ int   eoth[64];
  __shared__ float xT[64][66];     // [kk][token], stride 66: 8B-aligned float2
  __shared__ float w1c[64*DFFN];
  __shared__ float hwT[DFFN][72];  // [f][token]

  int tid = threadIdx.x;
  if (tid < 64) {
    int idx = (tid < R) ? (r0 + tid) : r0;
    int tok = bucket[MODE*16*NTOK + e*NTOK + idx];
    toks[tid] = tok;
    float4 rec = tokrec[tok];
    if (MODE == 0) { wself[tid] = rec.z; woth[tid] = rec.w; eoth[tid] = __float_as_int(rec.y); }
    else           { wself[tid] = rec.w; }
  }
  __syncthreads();

  float acc[2][4] = {};
  int tg = tid >> 3, fg = tid & 7;           // rows 2tg..2tg+1, cols 4fg..4fg+3
  const float* W1e = W1 + (size_t)e * D_MODEL * DFFN;
  int lr = tid >> 2, lq = tid & 3;

  for (int kc = 0; kc < D_MODEL; kc += 64) {
    const float* xrow = x + (size_t)toks[lr]*D_MODEL + kc + lq*16;
    float4 a0 = *(const float4*)(xrow + 0);
    float4 a1 = *(const float4*)(xrow + 4);
    float4 a2 = *(const float4*)(xrow + 8);
    float4 a3 = *(const float4*)(xrow + 12);
    const float4* w1g = (const float4*)(W1e + kc*DFFN);
    float4 wr0 = w1g[tid*2], wr1 = w1g[tid*2 + 1];
    __syncthreads();                          // previous chunk compute done
    int kb = lq * 16;
    xT[kb+ 0][lr]=a0.x; xT[kb+ 1][lr]=a0.y; xT[kb+ 2][lr]=a0.z; xT[kb+ 3][lr]=a0.w;
    xT[kb+ 4][lr]=a1.x; xT[kb+ 5][lr]=a1.y; xT[kb+ 6][lr]=a1.z; xT[kb+ 7][lr]=a1.w;
    xT[kb+ 8][lr]=a2.x; xT[kb+ 9][lr]=a2.y; xT[kb+10][lr]=a2.z; xT[kb+11][lr]=a2.w;
    xT[kb+12][lr]=a3.x; xT[kb+13][lr]=a3.y; xT[kb+14][lr]=a3.z; xT[kb+15][lr]=a3.w;
    ((float4*)w1c)[tid*2] = wr0; ((float4*)w1c)[tid*2 + 1] = wr1;
    __syncthreads();
    #pragma unroll
    for (int kk = 0; kk < 64; ++kk) {
      float2 xv = *(const float2*)&xT[kk][2*tg];
      float4 wv = *(const float4*)&w1c[kk*DFFN + 4*fg];
      acc[0][0] = fmaf(xv.x, wv.x, acc[0][0]);
      acc[0][1] = fmaf(xv.x, wv.y, acc[0][1]);
      acc[0][2] = fmaf(xv.x, wv.z, acc[0][2]);
      acc[0][3] = fmaf(xv.x, wv.w, acc[0][3]);
      acc[1][0] = fmaf(xv.y, wv.x, acc[1][0]);
      acc[1][1] = fmaf(xv.y, wv.y, acc[1][1]);
      acc[1][2] = fmaf(xv.y, wv.z, acc[1][2]);
      acc[1][3] = fmaf(xv.y, wv.w, acc[1][3]);
    }
  }
  // silu * w, write transposed
  #pragma unroll
  for (int tt = 0; tt < 2; ++tt) {
    int row = 2*tg + tt;
    float wsv = wself[row];
    #pragma unroll
    for (int ff = 0; ff < 4; ++ff) {
      int f = 4*fg + ff;
      float hp = acc[tt][ff] + b1[e*DFFN + f];
      float sg = 1.f / (1.f + __expf(-hp));
      hwT[f][row] = hp * sg * wsv;
    }
  }
  __syncthreads();

  // phase 2: out rows = hw @ W2 (+ biases in MODE 0)
  int d0 = tid << 2;
  const float* W2e = W2 + (size_t)e * DFFN * D_MODEL;
  const float* b2e = b2 + (size_t)e * D_MODEL;
  for (int g = 0; g < 8; ++g) {
    float4 acc2[8];
    #pragma unroll
    for (int t = 0; t < 8; ++t) {
      if (MODE == 0) {
        int row = 8*g + t;
        float4 bs = *(const float4*)(b2e + d0);
        float4 bo = *(const float4*)(b2 + (size_t)eoth[row]*D_MODEL + d0);
        float w0 = wself[row], w1 = woth[row];
        acc2[t] = make_float4(w0*bs.x + w1*bo.x, w0*bs.y + w1*bo.y,
                              w0*bs.z + w1*bo.z, w0*bs.w + w1*bo.w);
      } else {
        acc2[t] = make_float4(0.f, 0.f, 0.f, 0.f);
      }
    }
    #pragma unroll 8
    for (int f = 0; f < DFFN; ++f) {
      float4 w2v = *(const float4*)(W2e + (size_t)f*D_MODEL + d0);
      const float* hp = &hwT[f][8*g];
      #pragma unroll
      for (int t = 0; t < 8; ++t) {
        float hv = hp[t];
        acc2[t].x = fmaf(hv, w2v.x, acc2[t].x);
        acc2[t].y = fmaf(hv, w2v.y, acc2[t].y);
        acc2[t].z = fmaf(hv, w2v.z, acc2[t].z);
        acc2[t].w = fmaf(hv, w2v.w, acc2[t].w);
      }
    }
    #pragma unroll
    for (int t = 0; t < 8; ++t) {
      int row = 8*g + t;
      if (row < R) {
        float* op = out + (size_t)toks[row]*D_MODEL + d0;
        if (MODE == 0) {
          *(float4*)op = acc2[t];
        } else {
          atomAddF(op+0, acc2[t].x); atomAddF(op+1, acc2[t].y);
          atomAddF(op+2, acc2[t].z); atomAddF(op+3, acc2[t].w);
        }
      }
    }
  }
}

// ---------------- load-balance loss ----------------------------------------
__global__ void k_lb(const int* __restrict__ cnt, float* __restrict__ out) {
  if (threadIdx.x == 0 && blockIdx.x == 0) {
    float u[16]; float s = 0.f;
    for (int e = 0; e < 16; ++e) { u[e] = (float)(cnt[e] + cnt[16 + e]); s += u[e]; }
    float mean = s / 16.f;
    float var = 0.f;
    for (int e = 0; e < 16; ++e) { float d = u[e] - mean; var += d*d; }
    var /= 15.f;                               // ddof=1
    float m = mean + 1e-6f;
    out[OUT_LB] = var / (m*m);                 // (std/mean)^2
  }
}

extern "C" void kernel_launch(void* const* d_in, const int* in_sizes, int n_in,
                              void* d_out, int out_size, void* d_ws, size_t ws_size,
                              hipStream_t stream) {
  const float* x        = (const float*)d_in[0];
  const int*   task_id  = (const int*)  d_in[1];
  const float* task_emb = (const float*)d_in[2];
  const float* Wg       = (const float*)d_in[3];
  const float* bg       = (const float*)d_in[4];
  const float* W1       = (const float*)d_in[5];
  const float* b1       = (const float*)d_in[6];
  const float* W2       = (const float*)d_in[7];
  const float* b2       = (const float*)d_in[8];
  float* out = (float*)d_out;
  char* ws = (char*)d_ws;
  double* sums   = (double*)(ws + WS_SUMS);
  float*  wsf    = (float*) ws;
  float4* tokrec = (float4*)(ws + WS_TOKREC);
  int*    cnt    = (int*)   (ws + WS_CNT);
  int*    bucket = (int*)   (ws + WS_BUCKET);

  hipMemsetAsync(ws, 0, 1024, stream);
  k_stats<<<dim3(128, 4), 256, 0, stream>>>(x, sums);
  k_prep<<<1, 256, 0, stream>>>(sums, task_id, task_emb, Wg, bg, wsf);
  k_gating<<<NTOK/64, 256, 0, stream>>>(x, Wg, wsf, out, tokrec, cnt, bucket);
  k_ffn<0><<<dim3(256, 16), 256, 0, stream>>>(x, W1, b1, W2, b2, tokrec, cnt, bucket, out);
  k_ffn<1><<<dim3(256, 16), 256, 0, stream>>>(x, W1, b1, W2, b2, tokrec, cnt, bucket, out);
  k_lb<<<1, 64, 0, stream>>>(cnt, out);
}